// Round 1
// baseline (1089.655 us; speedup 1.0000x reference)
//
#include <hip/hip_runtime.h>
#include <stdint.h>
#include <stddef.h>

#define TOKS 4096
#define DH   2048
#define DI   8192

typedef __attribute__((ext_vector_type(8))) short short8v;
typedef __attribute__((ext_vector_type(4))) short short4v;
typedef __attribute__((ext_vector_type(4))) float floatx4;

__device__ __forceinline__ float b2f(short s) {
  union { unsigned u; float f; } v;
  v.u = ((unsigned)(unsigned short)s) << 16;
  return v.f;
}
__device__ __forceinline__ short f2b(float f) {
  union { float f; unsigned u; } v; v.f = f;
  unsigned r = (v.u + 0x7fffu + ((v.u >> 16) & 1u)) >> 16;  // RNE
  return (short)(unsigned short)r;
}
__device__ __forceinline__ void gload_lds16(const void* g, void* l) {
  __builtin_amdgcn_global_load_lds((const __attribute__((address_space(1))) void*)g,
                                   (__attribute__((address_space(3))) void*)l, 16, 0, 0);
}

// ---------------- fp32 -> bf16 elementwise (x) ----------------
__global__ __launch_bounds__(256) void cvt_f32_to_bf16(const float* __restrict__ in,
                                                       short* __restrict__ out) {
  size_t i = (size_t)blockIdx.x * 256 + threadIdx.x;
  floatx4 v = *(const floatx4*)&in[i * 4];
  short4v o;
  o[0] = f2b(v[0]); o[1] = f2b(v[1]); o[2] = f2b(v[2]); o[3] = f2b(v[3]);
  *(short4v*)&out[i * 4] = o;
}

// ---------------- fp32 [K][N] -> bf16 [N][K] transpose ----------------
__global__ __launch_bounds__(256) void transpose_to_bf16(const float* __restrict__ in,
                                                         short* __restrict__ out,
                                                         int K, int N) {
  __shared__ float tile[32][33];
  const int n0 = blockIdx.x * 32, k0 = blockIdx.y * 32;
  const int tx = threadIdx.x & 31, ty = threadIdx.x >> 5;  // ty: 0..7
#pragma unroll
  for (int yy = 0; yy < 32; yy += 8)
    tile[ty + yy][tx] = in[(size_t)(k0 + ty + yy) * N + n0 + tx];
  __syncthreads();
#pragma unroll
  for (int yy = 0; yy < 32; yy += 8)
    out[(size_t)(n0 + ty + yy) * K + k0 + tx] = f2b(tile[tx][ty + yy]);
}

// ---------------- router + const-expert gates (fp32 exact) ----------------
// Per token: logits = tanh(x@gw1)@gw2 ; softmax ; top-2 ; mask expert 7 ; renorm.
// Emits per-row scalars: coef = [coef_x, k0, k1, s_swiglu], and router_logits.
#define RT_TPB 16
__global__ __launch_bounds__(256) void router_kernel(const float* __restrict__ x,
                                                     const float* __restrict__ gw1,
                                                     const float* __restrict__ gw2,
                                                     const float* __restrict__ cwg,
                                                     float* __restrict__ logits_out,
                                                     float* __restrict__ coef) {
  const int wave = threadIdx.x >> 6, lane = threadIdx.x & 63;
  const int tok0 = blockIdx.x * RT_TPB;
  __shared__ float tpart[4][RT_TPB][64];  // 16 KB
  __shared__ float cpart[4][64];
  __shared__ float ll[RT_TPB][8];
  __shared__ float cd[RT_TPB][4];

  // phase 1: partial t[j] = sum_d x[tok][d]*gw1[d][j] over this wave's d-range
  float acc[RT_TPB];
#pragma unroll
  for (int t = 0; t < RT_TPB; ++t) acc[t] = 0.f;
  const int d0 = wave * 512;
  for (int d = d0; d < d0 + 512; ++d) {
    float g = gw1[d * 64 + lane];
#pragma unroll
    for (int t = 0; t < RT_TPB; ++t)
      acc[t] += x[(size_t)(tok0 + t) * DH + d] * g;
  }
#pragma unroll
  for (int t = 0; t < RT_TPB; ++t) tpart[wave][t][lane] = acc[t];

  // phase 1b: const-expert gate dots; lane -> (token = lane>>2, dot = lane&3)
  {
    const int t = lane >> 2, dotid = lane & 3;
    const int j = dotid >> 1, tt = dotid & 1;
    float a = 0.f;
    for (int d = d0; d < d0 + 512; ++d)
      a += x[(size_t)(tok0 + t) * DH + d] * cwg[(size_t)j * (DH * 2) + d * 2 + tt];
    cpart[wave][lane] = a;
  }
  __syncthreads();

  // phase 2: finish t, tanh, logits; wave handles tokens wave, wave+4, ...
  for (int t = wave; t < RT_TPB; t += 4) {
    float tj = tpart[0][t][lane] + tpart[1][t][lane] + tpart[2][t][lane] + tpart[3][t][lane];
    tj = tanhf(tj);
    float l[8];
#pragma unroll
    for (int e = 0; e < 8; ++e) {
      float p = tj * gw2[lane * 8 + e];
      for (int off = 32; off; off >>= 1) p += __shfl_xor(p, off);
      l[e] = p;
    }
    if (lane == 0) {
#pragma unroll
      for (int e = 0; e < 8; ++e) ll[t][e] = l[e];
    }
  }
  if (threadIdx.x < 64) {
    const int t = threadIdx.x >> 2, dotid = threadIdx.x & 3;
    cd[t][dotid] = cpart[0][threadIdx.x] + cpart[1][threadIdx.x] +
                   cpart[2][threadIdx.x] + cpart[3][threadIdx.x];
  }
  __syncthreads();

  // phase 3: per-token finalize (threads 0..15)
  if (threadIdx.x < RT_TPB) {
    const int t = threadIdx.x;
    const int gtok = tok0 + t;
    float l[8];
#pragma unroll
    for (int e = 0; e < 8; ++e) l[e] = ll[t][e];
#pragma unroll
    for (int e = 0; e < 8; ++e) logits_out[(size_t)gtok * 8 + e] = l[e];
    float m = l[0];
#pragma unroll
    for (int e = 1; e < 8; ++e) m = fmaxf(m, l[e]);
    float p[8], s = 0.f;
#pragma unroll
    for (int e = 0; e < 8; ++e) { p[e] = expf(l[e] - m); s += p[e]; }
#pragma unroll
    for (int e = 0; e < 8; ++e) p[e] /= s;
    // top-2, ties -> lowest index (strict >)
    int i1 = 0;
#pragma unroll
    for (int e = 1; e < 8; ++e) if (p[e] > p[i1]) i1 = e;
    int i2 = -1;
#pragma unroll
    for (int e = 0; e < 8; ++e) {
      if (e == i1) continue;
      if (i2 < 0 || p[e] > p[i2]) i2 = e;
    }
    float w1 = (i1 == 7) ? 0.f : p[i1];
    float w2 = (i2 == 7) ? 0.f : p[i2];
    const float nrm = w1 + w2;
    w1 /= nrm; w2 /= nrm;
    float pe[8];
#pragma unroll
    for (int e = 0; e < 8; ++e) pe[e] = 0.f;
    pe[i1] += w1; pe[i2] += w2;
    // const-expert gates: cw0 = sigmoid(a-b)
    const float cw00 = 1.f / (1.f + expf(cd[t][1] - cd[t][0]));
    const float cw10 = 1.f / (1.f + expf(cd[t][3] - cd[t][2]));
    coef[gtok * 4 + 0] = pe[0] + pe[2] * cw00 + pe[3] * cw10;
    coef[gtok * 4 + 1] = pe[2] * (1.f - cw00);
    coef[gtok * 4 + 2] = pe[3] * (1.f - cw10);
    coef[gtok * 4 + 3] = pe[4] + pe[5] + pe[6] + pe[7];
  }
}

// ---------------- bf16 MFMA GEMM mainloop (m97 structure) ----------------
// A [M][K] bf16 row-major, Bt [N][K] bf16 row-major. 128x128 tile, BK=32.
// 256 threads = 4 waves in 2x2; each wave does 4x4 MFMA tiles of 16x16x32.
__device__ __forceinline__ void gemm_mainloop(const short* __restrict__ A,
                                              const short* __restrict__ Bt,
                                              int K, int lda, int ldb,
                                              int m0, int n0,
                                              short* As, short* Bs,
                                              floatx4 (&acc)[4][4]) {
  const int wave = threadIdx.x >> 6;
  const int lane = threadIdx.x & 63;
  const int sr = lane >> 2;        // staging row within 16-row chunk
  const int sc = (lane & 3) * 8;   // staging col (bf16 elems)
  const int wm = (wave & 1) * 64;
  const int wn = (wave >> 1) * 64;
  const int q8 = (lane >> 4) * 8;
  const int l15 = lane & 15;

  for (int k0 = 0; k0 < K; k0 += 32) {
#pragma unroll
    for (int q = 0; q < 2; ++q) {
      const int chunk = wave * 2 + q;  // 16 rows per global_load_lds per wave
      gload_lds16(A + (size_t)(m0 + chunk * 16 + sr) * lda + k0 + sc,
                  &As[chunk * 16 * 32]);
      gload_lds16(Bt + (size_t)(n0 + chunk * 16 + sr) * ldb + k0 + sc,
                  &Bs[chunk * 16 * 32]);
    }
    __syncthreads();  // drains vmcnt -> LDS tiles valid
    short8v af[4], bf[4];
#pragma unroll
    for (int i = 0; i < 4; ++i) {
      af[i] = *(const short8v*)&As[(wm + i * 16 + l15) * 32 + q8];
      bf[i] = *(const short8v*)&Bs[(wn + i * 16 + l15) * 32 + q8];
    }
#pragma unroll
    for (int mi = 0; mi < 4; ++mi)
#pragma unroll
      for (int ni = 0; ni < 4; ++ni)
        acc[mi][ni] = __builtin_amdgcn_mfma_f32_16x16x32_bf16(af[mi], bf[ni],
                                                              acc[mi][ni], 0, 0, 0);
    __syncthreads();  // all waves done reading before next stage
  }
}

// GEMM1: C = A@B, bf16 out. C/D layout: col = lane&15, row = (lane>>4)*4 + reg.
__global__ __launch_bounds__(256) void gemm_bt_bf16(const short* __restrict__ A,
                                                    const short* __restrict__ Bt,
                                                    short* __restrict__ C,
                                                    int K, int lda, int ldb, int ldc) {
  __shared__ short As[128 * 32];
  __shared__ short Bs[128 * 32];
  floatx4 acc[4][4];
#pragma unroll
  for (int a = 0; a < 4; ++a)
#pragma unroll
    for (int b = 0; b < 4; ++b) acc[a][b] = (floatx4)0.0f;
  const int m0 = blockIdx.y * 128, n0 = blockIdx.x * 128;
  gemm_mainloop(A, Bt, K, lda, ldb, m0, n0, As, Bs, acc);
  const int wave = threadIdx.x >> 6, lane = threadIdx.x & 63;
  const int wm = (wave & 1) * 64, wn = (wave >> 1) * 64;
  const int l15 = lane & 15, q4 = (lane >> 4) * 4;
#pragma unroll
  for (int mi = 0; mi < 4; ++mi) {
    const int row0 = m0 + wm + mi * 16 + q4;
#pragma unroll
    for (int ni = 0; ni < 4; ++ni) {
      const int col = n0 + wn + ni * 16 + l15;
#pragma unroll
      for (int rg = 0; rg < 4; ++rg)
        C[(size_t)(row0 + rg) * ldc + col] = f2b(acc[mi][ni][rg]);
    }
  }
}

// GEMM2 with fused MoE epilogue:
// out[r][c] = cf.x * x[r][c] + cf.y * c0[c] + cf.z * c1[c] + cf.w * acc
__global__ __launch_bounds__(256) void gemm_bt_moe(const short* __restrict__ A,
                                                   const short* __restrict__ Bt,
                                                   float* __restrict__ out,
                                                   const float* __restrict__ x,
                                                   const float* __restrict__ cc,
                                                   const float* __restrict__ coef,
                                                   int K, int lda, int ldb) {
  __shared__ short As[128 * 32];
  __shared__ short Bs[128 * 32];
  floatx4 acc[4][4];
#pragma unroll
  for (int a = 0; a < 4; ++a)
#pragma unroll
    for (int b = 0; b < 4; ++b) acc[a][b] = (floatx4)0.0f;
  const int m0 = blockIdx.y * 128, n0 = blockIdx.x * 128;
  gemm_mainloop(A, Bt, K, lda, ldb, m0, n0, As, Bs, acc);
  const int wave = threadIdx.x >> 6, lane = threadIdx.x & 63;
  const int wm = (wave & 1) * 64, wn = (wave >> 1) * 64;
  const int l15 = lane & 15, q4 = (lane >> 4) * 4;
#pragma unroll
  for (int mi = 0; mi < 4; ++mi) {
    const int row0 = m0 + wm + mi * 16 + q4;
#pragma unroll
    for (int ni = 0; ni < 4; ++ni) {
      const int col = n0 + wn + ni * 16 + l15;
      const float c0v = cc[col];
      const float c1v = cc[DH + col];
#pragma unroll
      for (int rg = 0; rg < 4; ++rg) {
        const int row = row0 + rg;
        const floatx4 cf = *(const floatx4*)&coef[row * 4];
        out[(size_t)row * DH + col] =
            cf[0] * x[(size_t)row * DH + col] + cf[1] * c0v + cf[2] * c1v +
            cf[3] * acc[mi][ni][rg];
      }
    }
  }
}

// ---------------- silu(G)*U, in place over G half of GU ----------------
// GU is bf16 [4096][16384]: cols 0..8191 = G, 8192..16383 = U.
__global__ __launch_bounds__(256) void silu_mul_kernel(short* __restrict__ GU) {
  const size_t i = (size_t)blockIdx.x * 256 + threadIdx.x;
  const size_t r = i >> 10;               // 1024 8-elem chunks per row
  const int c = (int)(i & 1023) * 8;
  short8v g = *(const short8v*)&GU[r * 16384 + c];
  short8v u = *(const short8v*)&GU[r * 16384 + 8192 + c];
  short8v h;
#pragma unroll
  for (int e = 0; e < 8; ++e) {
    const float gf = b2f(g[e]);
    const float uf = b2f(u[e]);
    const float hv = (gf / (1.f + __expf(-gf))) * uf;
    h[e] = f2b(hv);
  }
  *(short8v*)&GU[r * 16384 + c] = h;
}

extern "C" void kernel_launch(void* const* d_in, const int* in_sizes, int n_in,
                              void* d_out, int out_size, void* d_ws, size_t ws_size,
                              hipStream_t stream) {
  const float* x   = (const float*)d_in[0];  // [4096][2048]
  const float* gw1 = (const float*)d_in[1];  // [2048][64]
  const float* gw2 = (const float*)d_in[2];  // [64][8]
  const float* cwg = (const float*)d_in[3];  // [2][2048][2]
  const float* cc  = (const float*)d_in[4];  // [2][2048]
  const float* wg  = (const float*)d_in[5];  // [2048][8192]
  const float* wu  = (const float*)d_in[6];  // [2048][8192]
  const float* wd  = (const float*)d_in[7];  // [8192][2048]
  float* out = (float*)d_out;
  float* logits_out = out + (size_t)TOKS * DH;  // tuple output #2

  char* ws = (char*)d_ws;
  short* xb    = (short*)(ws);                          // 16.78 MB
  short* wgwuT = (short*)(ws + 16777216);               // [16384][2048] bf16, 67.1 MB
  short* wdT   = (short*)(ws + 16777216 + 67108864);    // [2048][8192] bf16, 33.6 MB
  short* GU    = (short*)(ws + 117440512);              // [4096][16384] bf16, 134.2 MB
  float* coef  = (float*)(ws + 251658240);              // [4096][4] fp32

  // x -> bf16
  cvt_f32_to_bf16<<<(TOKS * DH) / (256 * 4), 256, 0, stream>>>(x, xb);
  // w_gate, w_up -> wgwuT (B^T layout, concatenated along N)
  transpose_to_bf16<<<dim3(DI / 32, DH / 32), 256, 0, stream>>>(wg, wgwuT, DH, DI);
  transpose_to_bf16<<<dim3(DI / 32, DH / 32), 256, 0, stream>>>(
      wu, wgwuT + (size_t)DI * DH, DH, DI);
  // w_down -> wdT
  transpose_to_bf16<<<dim3(DH / 32, DI / 32), 256, 0, stream>>>(wd, wdT, DI, DH);
  // router (also writes router_logits output)
  router_kernel<<<TOKS / RT_TPB, 256, 0, stream>>>(x, gw1, gw2, cwg, logits_out, coef);
  // GEMM1: [4096,2048] @ [2048,16384] -> GU bf16
  gemm_bt_bf16<<<dim3((2 * DI) / 128, TOKS / 128), 256, 0, stream>>>(
      xb, wgwuT, GU, DH, DH, DH, 2 * DI);
  // H = silu(G)*U in place over G half
  silu_mul_kernel<<<(TOKS * DI) / (256 * 8), 256, 0, stream>>>(GU);
  // GEMM2: [4096,8192] @ [8192,2048] -> out (fused MoE combine epilogue)
  gemm_bt_moe<<<dim3(DH / 128, TOKS / 128), 256, 0, stream>>>(
      GU, wdT, out, x, cc, coef, DI, 2 * DI, DI);
}

// Round 2
// 990.283 us; speedup vs baseline: 1.1003x; 1.1003x over previous
//
#include <hip/hip_runtime.h>
#include <stdint.h>
#include <stddef.h>

#define TOKS 4096
#define DH   2048
#define DI   8192

typedef __attribute__((ext_vector_type(8))) short short8v;
typedef __attribute__((ext_vector_type(4))) short short4v;
typedef __attribute__((ext_vector_type(4))) float floatx4;

__device__ __forceinline__ float b2f(short s) {
  union { unsigned u; float f; } v;
  v.u = ((unsigned)(unsigned short)s) << 16;
  return v.f;
}
__device__ __forceinline__ short f2b(float f) {
  union { float f; unsigned u; } v; v.f = f;
  unsigned r = (v.u + 0x7fffu + ((v.u >> 16) & 1u)) >> 16;  // RNE
  return (short)(unsigned short)r;
}
__device__ __forceinline__ void gload_lds16(const void* g, void* l) {
  __builtin_amdgcn_global_load_lds((const __attribute__((address_space(1))) void*)g,
                                   (__attribute__((address_space(3))) void*)l, 16, 0, 0);
}

// ---------------- fp32 -> bf16 elementwise (x) ----------------
__global__ __launch_bounds__(256) void cvt_f32_to_bf16(const float* __restrict__ in,
                                                       short* __restrict__ out) {
  size_t i = (size_t)blockIdx.x * 256 + threadIdx.x;
  floatx4 v = *(const floatx4*)&in[i * 4];
  short4v o;
  o[0] = f2b(v[0]); o[1] = f2b(v[1]); o[2] = f2b(v[2]); o[3] = f2b(v[3]);
  *(short4v*)&out[i * 4] = o;
}

// ---------- fp32 [K][N] -> bf16 [N][K] transpose (strided/interleaved out) ----
// out logical row n lands at physical row n*rstride + roff.
__global__ __launch_bounds__(256) void transpose_to_bf16(const float* __restrict__ in,
                                                         short* __restrict__ out,
                                                         int K, int N,
                                                         int rstride, int roff) {
  __shared__ float tile[32][33];
  const int n0 = blockIdx.x * 32, k0 = blockIdx.y * 32;
  const int tx = threadIdx.x & 31, ty = threadIdx.x >> 5;  // ty: 0..7
#pragma unroll
  for (int yy = 0; yy < 32; yy += 8)
    tile[ty + yy][tx] = in[(size_t)(k0 + ty + yy) * N + n0 + tx];
  __syncthreads();
#pragma unroll
  for (int yy = 0; yy < 32; yy += 8)
    out[((size_t)(n0 + ty + yy) * rstride + roff) * K + k0 + tx] = f2b(tile[tx][ty + yy]);
}

// ---------------- router + const-expert gates (fp32 exact) ----------------
#define RT_TPB 16
__global__ __launch_bounds__(256) void router_kernel(const float* __restrict__ x,
                                                     const float* __restrict__ gw1,
                                                     const float* __restrict__ gw2,
                                                     const float* __restrict__ cwg,
                                                     float* __restrict__ logits_out,
                                                     float* __restrict__ coef) {
  const int wave = threadIdx.x >> 6, lane = threadIdx.x & 63;
  const int tok0 = blockIdx.x * RT_TPB;
  __shared__ float tpart[4][RT_TPB][64];  // 16 KB
  __shared__ float cpart[4][64];
  __shared__ float ll[RT_TPB][8];
  __shared__ float cd[RT_TPB][4];

  float acc[RT_TPB];
#pragma unroll
  for (int t = 0; t < RT_TPB; ++t) acc[t] = 0.f;
  const int d0 = wave * 512;
  for (int d = d0; d < d0 + 512; ++d) {
    float g = gw1[d * 64 + lane];
#pragma unroll
    for (int t = 0; t < RT_TPB; ++t)
      acc[t] += x[(size_t)(tok0 + t) * DH + d] * g;
  }
#pragma unroll
  for (int t = 0; t < RT_TPB; ++t) tpart[wave][t][lane] = acc[t];

  {
    const int t = lane >> 2, dotid = lane & 3;
    const int j = dotid >> 1, tt = dotid & 1;
    float a = 0.f;
    for (int d = d0; d < d0 + 512; ++d)
      a += x[(size_t)(tok0 + t) * DH + d] * cwg[(size_t)j * (DH * 2) + d * 2 + tt];
    cpart[wave][lane] = a;
  }
  __syncthreads();

  for (int t = wave; t < RT_TPB; t += 4) {
    float tj = tpart[0][t][lane] + tpart[1][t][lane] + tpart[2][t][lane] + tpart[3][t][lane];
    tj = tanhf(tj);
    float l[8];
#pragma unroll
    for (int e = 0; e < 8; ++e) {
      float p = tj * gw2[lane * 8 + e];
      for (int off = 32; off; off >>= 1) p += __shfl_xor(p, off);
      l[e] = p;
    }
    if (lane == 0) {
#pragma unroll
      for (int e = 0; e < 8; ++e) ll[t][e] = l[e];
    }
  }
  if (threadIdx.x < 64) {
    const int t = threadIdx.x >> 2, dotid = threadIdx.x & 3;
    cd[t][dotid] = cpart[0][threadIdx.x] + cpart[1][threadIdx.x] +
                   cpart[2][threadIdx.x] + cpart[3][threadIdx.x];
  }
  __syncthreads();

  if (threadIdx.x < RT_TPB) {
    const int t = threadIdx.x;
    const int gtok = tok0 + t;
    float l[8];
#pragma unroll
    for (int e = 0; e < 8; ++e) l[e] = ll[t][e];
#pragma unroll
    for (int e = 0; e < 8; ++e) logits_out[(size_t)gtok * 8 + e] = l[e];
    float m = l[0];
#pragma unroll
    for (int e = 1; e < 8; ++e) m = fmaxf(m, l[e]);
    float p[8], s = 0.f;
#pragma unroll
    for (int e = 0; e < 8; ++e) { p[e] = expf(l[e] - m); s += p[e]; }
#pragma unroll
    for (int e = 0; e < 8; ++e) p[e] /= s;
    int i1 = 0;
#pragma unroll
    for (int e = 1; e < 8; ++e) if (p[e] > p[i1]) i1 = e;
    int i2 = -1;
#pragma unroll
    for (int e = 0; e < 8; ++e) {
      if (e == i1) continue;
      if (i2 < 0 || p[e] > p[i2]) i2 = e;
    }
    float w1 = (i1 == 7) ? 0.f : p[i1];
    float w2 = (i2 == 7) ? 0.f : p[i2];
    const float nrm = w1 + w2;
    w1 /= nrm; w2 /= nrm;
    float pe[8];
#pragma unroll
    for (int e = 0; e < 8; ++e) pe[e] = 0.f;
    pe[i1] += w1; pe[i2] += w2;
    const float cw00 = 1.f / (1.f + expf(cd[t][1] - cd[t][0]));
    const float cw10 = 1.f / (1.f + expf(cd[t][3] - cd[t][2]));
    coef[gtok * 4 + 0] = pe[0] + pe[2] * cw00 + pe[3] * cw10;
    coef[gtok * 4 + 1] = pe[2] * (1.f - cw00);
    coef[gtok * 4 + 2] = pe[3] * (1.f - cw10);
    coef[gtok * 4 + 3] = pe[4] + pe[5] + pe[6] + pe[7];
  }
}

// ---------------- bf16 MFMA GEMM mainloop (m97 structure + XOR swizzle) -------
// A [M][K] bf16 row-major, Bt [N][K] bf16 row-major. 128x128 tile, BK=32.
// LDS quarter (16 B) of row r holds global quarter q ^ ((r>>1)&3): makes every
// 16-lane ds_read_b128 group hit each 4-bank group exactly 2x (free, m136).
__device__ __forceinline__ void gemm_mainloop(const short* __restrict__ A,
                                              const short* __restrict__ Bt,
                                              int K, int lda, int ldb,
                                              int m0, int n0,
                                              short* As, short* Bs,
                                              floatx4 (&acc)[4][4]) {
  const int wave = threadIdx.x >> 6;
  const int lane = threadIdx.x & 63;
  const int sr = lane >> 2;                                 // staging row in 16-row chunk
  const int sc = ((lane & 3) ^ ((sr >> 1) & 3)) * 8;        // swizzled source quarter
  const int wm = (wave & 1) * 64;
  const int wn = (wave >> 1) * 64;
  const int l15 = lane & 15;
  const int qf = (((lane >> 4) ^ ((l15 >> 1) & 3))) * 8;    // swizzled read quarter

  for (int k0 = 0; k0 < K; k0 += 32) {
#pragma unroll
    for (int q = 0; q < 2; ++q) {
      const int chunk = wave * 2 + q;  // 16 rows per global_load_lds per wave
      gload_lds16(A + (size_t)(m0 + chunk * 16 + sr) * lda + k0 + sc,
                  &As[chunk * 16 * 32]);
      gload_lds16(Bt + (size_t)(n0 + chunk * 16 + sr) * ldb + k0 + sc,
                  &Bs[chunk * 16 * 32]);
    }
    __syncthreads();
    short8v af[4], bf[4];
#pragma unroll
    for (int i = 0; i < 4; ++i) {
      af[i] = *(const short8v*)&As[(wm + i * 16 + l15) * 32 + qf];
      bf[i] = *(const short8v*)&Bs[(wn + i * 16 + l15) * 32 + qf];
    }
#pragma unroll
    for (int mi = 0; mi < 4; ++mi)
#pragma unroll
      for (int ni = 0; ni < 4; ++ni)
        acc[mi][ni] = __builtin_amdgcn_mfma_f32_16x16x32_bf16(af[mi], bf[ni],
                                                              acc[mi][ni], 0, 0, 0);
    __syncthreads();
  }
}

// GEMM1 fused: Bt holds interleaved [2n]=g_col n, [2n+1]=u_col n. Epilogue pairs
// even/odd lanes via shfl_xor and writes H = silu(g)*u, [4096][8192] bf16.
__global__ __launch_bounds__(256) void gemm1_gu_silu(const short* __restrict__ A,
                                                     const short* __restrict__ Bt,
                                                     short* __restrict__ H,
                                                     int K, int lda, int ldb) {
  __shared__ short As[128 * 32];
  __shared__ short Bs[128 * 32];
  floatx4 acc[4][4];
#pragma unroll
  for (int a = 0; a < 4; ++a)
#pragma unroll
    for (int b = 0; b < 4; ++b) acc[a][b] = (floatx4)0.0f;
  // raster remap: 32 consecutive blocks share one B panel (0.5 MB), A streams L2
  const int lin = blockIdx.y * gridDim.x + blockIdx.x;
  const int m0 = (lin & 31) * 128, n0 = (lin >> 5) * 128;
  gemm_mainloop(A, Bt, K, lda, ldb, m0, n0, As, Bs, acc);
  const int wave = threadIdx.x >> 6, lane = threadIdx.x & 63;
  const int wm = (wave & 1) * 64, wn = (wave >> 1) * 64;
  const int l15 = lane & 15, q4 = (lane >> 4) * 4;
#pragma unroll
  for (int mi = 0; mi < 4; ++mi) {
    const int row0 = m0 + wm + mi * 16 + q4;
#pragma unroll
    for (int ni = 0; ni < 4; ++ni) {
      const int col = n0 + wn + ni * 16 + l15;  // interleaved col
#pragma unroll
      for (int rg = 0; rg < 4; ++rg) {
        const float v = acc[mi][ni][rg];
        const float p = __shfl_xor(v, 1);   // partner (g<->u)
        if ((l15 & 1) == 0) {
          const float h = (v / (1.f + __expf(-v))) * p;  // silu(g)*u
          H[(size_t)(row0 + rg) * DI + (col >> 1)] = f2b(h);
        }
      }
    }
  }
}

// GEMM2 with fused MoE epilogue:
// out[r][c] = cf.x * x[r][c] + cf.y * c0[c] + cf.z * c1[c] + cf.w * acc
__global__ __launch_bounds__(256) void gemm_bt_moe(const short* __restrict__ A,
                                                   const short* __restrict__ Bt,
                                                   float* __restrict__ out,
                                                   const float* __restrict__ x,
                                                   const float* __restrict__ cc,
                                                   const float* __restrict__ coef,
                                                   int K, int lda, int ldb) {
  __shared__ short As[128 * 32];
  __shared__ short Bs[128 * 32];
  floatx4 acc[4][4];
#pragma unroll
  for (int a = 0; a < 4; ++a)
#pragma unroll
    for (int b = 0; b < 4; ++b) acc[a][b] = (floatx4)0.0f;
  const int lin = blockIdx.y * gridDim.x + blockIdx.x;
  const int m0 = (lin & 31) * 128, n0 = (lin >> 5) * 128;
  gemm_mainloop(A, Bt, K, lda, ldb, m0, n0, As, Bs, acc);
  const int wave = threadIdx.x >> 6, lane = threadIdx.x & 63;
  const int wm = (wave & 1) * 64, wn = (wave >> 1) * 64;
  const int l15 = lane & 15, q4 = (lane >> 4) * 4;
#pragma unroll
  for (int mi = 0; mi < 4; ++mi) {
    const int row0 = m0 + wm + mi * 16 + q4;
#pragma unroll
    for (int ni = 0; ni < 4; ++ni) {
      const int col = n0 + wn + ni * 16 + l15;
      const float c0v = cc[col];
      const float c1v = cc[DH + col];
#pragma unroll
      for (int rg = 0; rg < 4; ++rg) {
        const int row = row0 + rg;
        const floatx4 cf = *(const floatx4*)&coef[row * 4];
        out[(size_t)row * DH + col] =
            cf[0] * x[(size_t)row * DH + col] + cf[1] * c0v + cf[2] * c1v +
            cf[3] * acc[mi][ni][rg];
      }
    }
  }
}

extern "C" void kernel_launch(void* const* d_in, const int* in_sizes, int n_in,
                              void* d_out, int out_size, void* d_ws, size_t ws_size,
                              hipStream_t stream) {
  const float* x   = (const float*)d_in[0];  // [4096][2048]
  const float* gw1 = (const float*)d_in[1];  // [2048][64]
  const float* gw2 = (const float*)d_in[2];  // [64][8]
  const float* cwg = (const float*)d_in[3];  // [2][2048][2]
  const float* cc  = (const float*)d_in[4];  // [2][2048]
  const float* wg  = (const float*)d_in[5];  // [2048][8192]
  const float* wu  = (const float*)d_in[6];  // [2048][8192]
  const float* wd  = (const float*)d_in[7];  // [8192][2048]
  float* out = (float*)d_out;
  float* logits_out = out + (size_t)TOKS * DH;  // tuple output #2

  char* ws = (char*)d_ws;
  short* xb    = (short*)(ws);                          // 16.78 MB
  short* wgwuT = (short*)(ws + 16777216);               // [16384][2048] bf16 interleaved, 67.1 MB
  short* wdT   = (short*)(ws + 16777216 + 67108864);    // [2048][8192] bf16, 33.6 MB
  short* H     = (short*)(ws + 117440512);              // [4096][8192] bf16, 67.1 MB
  float* coef  = (float*)(ws + 117440512 + 67108864);   // [4096][4] fp32

  // x -> bf16
  cvt_f32_to_bf16<<<(TOKS * DH) / (256 * 4), 256, 0, stream>>>(x, xb);
  // w_gate -> even rows, w_up -> odd rows of interleaved B^T
  transpose_to_bf16<<<dim3(DI / 32, DH / 32), 256, 0, stream>>>(wg, wgwuT, DH, DI, 2, 0);
  transpose_to_bf16<<<dim3(DI / 32, DH / 32), 256, 0, stream>>>(wu, wgwuT, DH, DI, 2, 1);
  // w_down -> wdT
  transpose_to_bf16<<<dim3(DH / 32, DI / 32), 256, 0, stream>>>(wd, wdT, DI, DH, 1, 0);
  // router (also writes router_logits output)
  router_kernel<<<TOKS / RT_TPB, 256, 0, stream>>>(x, gw1, gw2, cwg, logits_out, coef);
  // GEMM1 fused: [4096,2048] @ [2048,16384 interleaved] -> H = silu(G)*U bf16
  gemm1_gu_silu<<<dim3((2 * DI) / 128, TOKS / 128), 256, 0, stream>>>(
      xb, wgwuT, H, DH, DH, DH);
  // GEMM2: [4096,8192] @ [8192,2048] -> out (fused MoE combine epilogue)
  gemm_bt_moe<<<dim3(DH / 128, TOKS / 128), 256, 0, stream>>>(
      H, wdT, out, x, cc, coef, DI, DI, DI);
}

// Round 3
// 860.056 us; speedup vs baseline: 1.2670x; 1.1514x over previous
//
#include <hip/hip_runtime.h>
#include <stdint.h>
#include <stddef.h>

#define TOKS 4096
#define DH   2048
#define DI   8192

typedef __attribute__((ext_vector_type(8))) short short8v;
typedef __attribute__((ext_vector_type(4))) short short4v;
typedef __attribute__((ext_vector_type(4))) float floatx4;

__device__ __forceinline__ float b2f(short s) {
  union { unsigned u; float f; } v;
  v.u = ((unsigned)(unsigned short)s) << 16;
  return v.f;
}
__device__ __forceinline__ short f2b(float f) {
  union { float f; unsigned u; } v; v.f = f;
  unsigned r = (v.u + 0x7fffu + ((v.u >> 16) & 1u)) >> 16;  // RNE
  return (short)(unsigned short)r;
}
__device__ __forceinline__ void gload_lds16(const void* g, void* l) {
  __builtin_amdgcn_global_load_lds((const __attribute__((address_space(1))) void*)g,
                                   (__attribute__((address_space(3))) void*)l, 16, 0, 0);
}

// ---------------- fp32 -> bf16 elementwise (x) ----------------
__global__ __launch_bounds__(256) void cvt_f32_to_bf16(const float* __restrict__ in,
                                                       short* __restrict__ out) {
  size_t i = (size_t)blockIdx.x * 256 + threadIdx.x;
  floatx4 v = *(const floatx4*)&in[i * 4];
  short4v o;
  o[0] = f2b(v[0]); o[1] = f2b(v[1]); o[2] = f2b(v[2]); o[3] = f2b(v[3]);
  *(short4v*)&out[i * 4] = o;
}

// ---------- fp32 [K][N] -> bf16 [N][K] transpose (strided/interleaved out) ----
__global__ __launch_bounds__(256) void transpose_to_bf16(const float* __restrict__ in,
                                                         short* __restrict__ out,
                                                         int K, int N,
                                                         int rstride, int roff) {
  __shared__ float tile[32][33];
  const int n0 = blockIdx.x * 32, k0 = blockIdx.y * 32;
  const int tx = threadIdx.x & 31, ty = threadIdx.x >> 5;  // ty: 0..7
#pragma unroll
  for (int yy = 0; yy < 32; yy += 8)
    tile[ty + yy][tx] = in[(size_t)(k0 + ty + yy) * N + n0 + tx];
  __syncthreads();
#pragma unroll
  for (int yy = 0; yy < 32; yy += 8)
    out[((size_t)(n0 + ty + yy) * rstride + roff) * K + k0 + tx] = f2b(tile[tx][ty + yy]);
}

// ---------------- router + const-expert gates (fp32 exact) ----------------
// 8 tokens/block, 512 blocks. x staged through LDS in 512-d chunks; each wave
// owns 2 tokens, accumulates tj[col=lane] over all 2048 d via LDS broadcast.
#define RT_TPB 8
__global__ __launch_bounds__(256) void router_kernel(const float* __restrict__ x,
                                                     const float* __restrict__ gw1,
                                                     const float* __restrict__ gw2,
                                                     const float* __restrict__ cwg,
                                                     float* __restrict__ logits_out,
                                                     float* __restrict__ coef) {
  const int wave = threadIdx.x >> 6, lane = threadIdx.x & 63;
  const int tok0 = blockIdx.x * RT_TPB;
  __shared__ float xs[RT_TPB][512];   // 16 KB chunk
  __shared__ float ll[RT_TPB][8];
  __shared__ float cd[RT_TPB][4];

  float tj[2] = {0.f, 0.f};           // gate-hidden partial, col = lane
  float cda[2][4] = {{0.f,0.f,0.f,0.f},{0.f,0.f,0.f,0.f}};  // const-dot partials

  const int st = threadIdx.x >> 5;        // staging token 0..7
  const int sl = threadIdx.x & 31;

  for (int c = 0; c < 4; ++c) {
    const int dbase = c * 512;
#pragma unroll
    for (int r = 0; r < 4; ++r) {
      const int idx = r * 128 + sl * 4;
      *(floatx4*)&xs[st][idx] = *(const floatx4*)&x[(size_t)(tok0 + st) * DH + dbase + idx];
    }
    __syncthreads();
    // tj accumulation: wave's 2 tokens, all 512 d of this chunk
    for (int d = 0; d < 512; ++d) {
      const float g = gw1[(size_t)(dbase + d) * 64 + lane];
      tj[0] += xs[wave * 2 + 0][d] * g;
      tj[1] += xs[wave * 2 + 1][d] * g;
    }
    // const-expert dots: lane-strided over d; dd = j*2+tt
#pragma unroll
    for (int dq = 0; dq < 8; ++dq) {
      const int d = dq * 64 + lane;
      const float w0 = cwg[(size_t)(dbase + d) * 2 + 0];
      const float w1 = cwg[(size_t)(dbase + d) * 2 + 1];
      const float w2 = cwg[(size_t)DH * 2 + (dbase + d) * 2 + 0];
      const float w3 = cwg[(size_t)DH * 2 + (dbase + d) * 2 + 1];
#pragma unroll
      for (int t = 0; t < 2; ++t) {
        const float xv = xs[wave * 2 + t][d];
        cda[t][0] += xv * w0; cda[t][1] += xv * w1;
        cda[t][2] += xv * w2; cda[t][3] += xv * w3;
      }
    }
    __syncthreads();
  }

  // logits: tanh then project by gw2; shuffle-reduce over 64 lanes
#pragma unroll
  for (int t = 0; t < 2; ++t) {
    const float th = tanhf(tj[t]);
#pragma unroll
    for (int e = 0; e < 8; ++e) {
      float p = th * gw2[lane * 8 + e];
      for (int off = 32; off; off >>= 1) p += __shfl_xor(p, off);
      if (lane == 0) ll[wave * 2 + t][e] = p;
    }
#pragma unroll
    for (int dd = 0; dd < 4; ++dd) {
      float p = cda[t][dd];
      for (int off = 32; off; off >>= 1) p += __shfl_xor(p, off);
      if (lane == 0) cd[wave * 2 + t][dd] = p;
    }
  }
  __syncthreads();

  if (threadIdx.x < RT_TPB) {
    const int t = threadIdx.x;
    const int gtok = tok0 + t;
    float l[8];
#pragma unroll
    for (int e = 0; e < 8; ++e) l[e] = ll[t][e];
#pragma unroll
    for (int e = 0; e < 8; ++e) logits_out[(size_t)gtok * 8 + e] = l[e];
    float m = l[0];
#pragma unroll
    for (int e = 1; e < 8; ++e) m = fmaxf(m, l[e]);
    float p[8], s = 0.f;
#pragma unroll
    for (int e = 0; e < 8; ++e) { p[e] = expf(l[e] - m); s += p[e]; }
#pragma unroll
    for (int e = 0; e < 8; ++e) p[e] /= s;
    int i1 = 0;
#pragma unroll
    for (int e = 1; e < 8; ++e) if (p[e] > p[i1]) i1 = e;
    int i2 = -1;
#pragma unroll
    for (int e = 0; e < 8; ++e) {
      if (e == i1) continue;
      if (i2 < 0 || p[e] > p[i2]) i2 = e;
    }
    float w1 = (i1 == 7) ? 0.f : p[i1];
    float w2 = (i2 == 7) ? 0.f : p[i2];
    const float nrm = w1 + w2;
    w1 /= nrm; w2 /= nrm;
    float pe[8];
#pragma unroll
    for (int e = 0; e < 8; ++e) pe[e] = 0.f;
    pe[i1] += w1; pe[i2] += w2;
    const float cw00 = 1.f / (1.f + expf(cd[t][1] - cd[t][0]));
    const float cw10 = 1.f / (1.f + expf(cd[t][3] - cd[t][2]));
    coef[gtok * 4 + 0] = pe[0] + pe[2] * cw00 + pe[3] * cw10;
    coef[gtok * 4 + 1] = pe[2] * (1.f - cw00);
    coef[gtok * 4 + 2] = pe[3] * (1.f - cw10);
    coef[gtok * 4 + 3] = pe[4] + pe[5] + pe[6] + pe[7];
  }
}

// ---------------- bf16 MFMA GEMM mainloop: BK=64, XOR-swizzled LDS ----------
// A [M][K], Bt [N][K] bf16 row-major. 128x128 tile, BK=64: 32 MFMA per barrier
// pair. LDS row = 128 B = 32 banks; 16B-quarter q of row r stored at q^(r&7)
// -> even 8-lane-per-bank-group distribution on ds_read_b128 (throughput floor).
__device__ __forceinline__ void gemm_mainloop(const short* __restrict__ A,
                                              const short* __restrict__ Bt,
                                              int K, int lda, int ldb,
                                              int m0, int n0,
                                              short* As, short* Bs,
                                              floatx4 (&acc)[4][4]) {
  const int wave = threadIdx.x >> 6;
  const int lane = threadIdx.x & 63;
  const int srow = lane >> 3;                   // row within 8-row staging chunk
  const int scol = ((lane & 7) ^ srow) * 8;     // swizzled source quarter (elems)
  const int wm = (wave & 1) * 64;
  const int wn = (wave >> 1) * 64;
  const int l15 = lane & 15;
  const int quad = lane >> 4;
  const int q0 = ((quad ^ (l15 & 7)) * 8);      // kk=0 read quarter offset (elems)

  for (int k0 = 0; k0 < K; k0 += 64) {
#pragma unroll
    for (int q = 0; q < 4; ++q) {
      const int chunk = wave * 4 + q;           // 16 chunks x 8 rows = 128 rows
      const int row = chunk * 8 + srow;
      gload_lds16(A + (size_t)(m0 + row) * lda + k0 + scol, &As[chunk * 8 * 64]);
      gload_lds16(Bt + (size_t)(n0 + row) * ldb + k0 + scol, &Bs[chunk * 8 * 64]);
    }
    __syncthreads();
#pragma unroll
    for (int kk = 0; kk < 2; ++kk) {
      const int qo = q0 ^ (kk * 32);            // (kk*4+quad)^(l15&7) in elems
      short8v af[4], bf[4];
#pragma unroll
      for (int i = 0; i < 4; ++i) {
        af[i] = *(const short8v*)&As[(wm + i * 16 + l15) * 64 + qo];
        bf[i] = *(const short8v*)&Bs[(wn + i * 16 + l15) * 64 + qo];
      }
#pragma unroll
      for (int mi = 0; mi < 4; ++mi)
#pragma unroll
        for (int ni = 0; ni < 4; ++ni)
          acc[mi][ni] = __builtin_amdgcn_mfma_f32_16x16x32_bf16(af[mi], bf[ni],
                                                                acc[mi][ni], 0, 0, 0);
    }
    __syncthreads();
  }
}

// GEMM1 fused: Bt interleaved [2n]=g_col n, [2n+1]=u_col n. Writes H=silu(g)*u.
__global__ __launch_bounds__(256) void gemm1_gu_silu(const short* __restrict__ A,
                                                     const short* __restrict__ Bt,
                                                     short* __restrict__ H,
                                                     int K, int lda, int ldb) {
  __shared__ short As[128 * 64];
  __shared__ short Bs[128 * 64];
  floatx4 acc[4][4];
#pragma unroll
  for (int a = 0; a < 4; ++a)
#pragma unroll
    for (int b = 0; b < 4; ++b) acc[a][b] = (floatx4)0.0f;
  const int lin = blockIdx.y * gridDim.x + blockIdx.x;
  const int m0 = (lin & 31) * 128, n0 = (lin >> 5) * 128;
  gemm_mainloop(A, Bt, K, lda, ldb, m0, n0, As, Bs, acc);
  const int wave = threadIdx.x >> 6, lane = threadIdx.x & 63;
  const int wm = (wave & 1) * 64, wn = (wave >> 1) * 64;
  const int l15 = lane & 15, q4 = (lane >> 4) * 4;
#pragma unroll
  for (int mi = 0; mi < 4; ++mi) {
    const int row0 = m0 + wm + mi * 16 + q4;
#pragma unroll
    for (int ni = 0; ni < 4; ++ni) {
      const int col = n0 + wn + ni * 16 + l15;  // interleaved col
#pragma unroll
      for (int rg = 0; rg < 4; ++rg) {
        const float v = acc[mi][ni][rg];
        const float p = __shfl_xor(v, 1);   // partner (g<->u)
        if ((l15 & 1) == 0) {
          const float h = (v / (1.f + __expf(-v))) * p;  // silu(g)*u
          H[(size_t)(row0 + rg) * DI + (col >> 1)] = f2b(h);
        }
      }
    }
  }
}

// GEMM2 with fused MoE epilogue.
__global__ __launch_bounds__(256) void gemm_bt_moe(const short* __restrict__ A,
                                                   const short* __restrict__ Bt,
                                                   float* __restrict__ out,
                                                   const float* __restrict__ x,
                                                   const float* __restrict__ cc,
                                                   const float* __restrict__ coef,
                                                   int K, int lda, int ldb) {
  __shared__ short As[128 * 64];
  __shared__ short Bs[128 * 64];
  floatx4 acc[4][4];
#pragma unroll
  for (int a = 0; a < 4; ++a)
#pragma unroll
    for (int b = 0; b < 4; ++b) acc[a][b] = (floatx4)0.0f;
  const int lin = blockIdx.y * gridDim.x + blockIdx.x;
  const int m0 = (lin & 31) * 128, n0 = (lin >> 5) * 128;
  gemm_mainloop(A, Bt, K, lda, ldb, m0, n0, As, Bs, acc);
  const int wave = threadIdx.x >> 6, lane = threadIdx.x & 63;
  const int wm = (wave & 1) * 64, wn = (wave >> 1) * 64;
  const int l15 = lane & 15, q4 = (lane >> 4) * 4;
#pragma unroll
  for (int mi = 0; mi < 4; ++mi) {
    const int row0 = m0 + wm + mi * 16 + q4;
#pragma unroll
    for (int ni = 0; ni < 4; ++ni) {
      const int col = n0 + wn + ni * 16 + l15;
      const float c0v = cc[col];
      const float c1v = cc[DH + col];
#pragma unroll
      for (int rg = 0; rg < 4; ++rg) {
        const int row = row0 + rg;
        const floatx4 cf = *(const floatx4*)&coef[row * 4];
        out[(size_t)row * DH + col] =
            cf[0] * x[(size_t)row * DH + col] + cf[1] * c0v + cf[2] * c1v +
            cf[3] * acc[mi][ni][rg];
      }
    }
  }
}

extern "C" void kernel_launch(void* const* d_in, const int* in_sizes, int n_in,
                              void* d_out, int out_size, void* d_ws, size_t ws_size,
                              hipStream_t stream) {
  const float* x   = (const float*)d_in[0];
  const float* gw1 = (const float*)d_in[1];
  const float* gw2 = (const float*)d_in[2];
  const float* cwg = (const float*)d_in[3];
  const float* cc  = (const float*)d_in[4];
  const float* wg  = (const float*)d_in[5];
  const float* wu  = (const float*)d_in[6];
  const float* wd  = (const float*)d_in[7];
  float* out = (float*)d_out;
  float* logits_out = out + (size_t)TOKS * DH;

  char* ws = (char*)d_ws;
  short* xb    = (short*)(ws);                          // 16.78 MB
  short* wgwuT = (short*)(ws + 16777216);               // [16384][2048] bf16 interleaved
  short* wdT   = (short*)(ws + 16777216 + 67108864);    // [2048][8192] bf16
  short* H     = (short*)(ws + 117440512);              // [4096][8192] bf16
  float* coef  = (float*)(ws + 117440512 + 67108864);   // [4096][4] fp32

  cvt_f32_to_bf16<<<(TOKS * DH) / (256 * 4), 256, 0, stream>>>(x, xb);
  transpose_to_bf16<<<dim3(DI / 32, DH / 32), 256, 0, stream>>>(wg, wgwuT, DH, DI, 2, 0);
  transpose_to_bf16<<<dim3(DI / 32, DH / 32), 256, 0, stream>>>(wu, wgwuT, DH, DI, 2, 1);
  transpose_to_bf16<<<dim3(DH / 32, DI / 32), 256, 0, stream>>>(wd, wdT, DI, DH, 1, 0);
  router_kernel<<<TOKS / RT_TPB, 256, 0, stream>>>(x, gw1, gw2, cwg, logits_out, coef);
  gemm1_gu_silu<<<dim3((2 * DI) / 128, TOKS / 128), 256, 0, stream>>>(
      xb, wgwuT, H, DH, DH, DH);
  gemm_bt_moe<<<dim3(DH / 128, TOKS / 128), 256, 0, stream>>>(
      H, wdT, out, x, cc, coef, DI, DI, DI);
}